// Round 1
// baseline (180.712 us; speedup 1.0000x reference)
//
#include <hip/hip_runtime.h>
#include <cstdint>

// Problem constants: view1 (B=8, C=4, H=256, W=256) fp32, F 3x3 fp32.
constexpr int Hh = 256, Ww = 256, BCc = 32;   // BC = B*C = 32 channels
constexpr int CH_PER = 8;                      // channels per thread
constexpr int SPLITS = BCc / CH_PER;           // 4 threads per pixel

// Transpose (B,C,H,W) -> T[r][u][ch]  (T[i*32+ch] = in[ch*65536+i], i=r*W+u).
// Reads are coalesced per channel plane; writes are 128B/thread contiguous.
__global__ __launch_bounds__(256) void fume_transpose(const float* __restrict__ in,
                                                      float* __restrict__ T) {
    int i = blockIdx.x * 256 + threadIdx.x;   // 0..65535
    float vals[BCc];
#pragma unroll
    for (int ch = 0; ch < BCc; ++ch) vals[ch] = in[ch * (Hh * Ww) + i];
    float4* dst = reinterpret_cast<float4*>(T + (size_t)i * BCc);
#pragma unroll
    for (int k = 0; k < BCc / 4; ++k)
        dst[k] = make_float4(vals[4*k+0], vals[4*k+1], vals[4*k+2], vals[4*k+3]);
}

// Main: one thread handles CH_PER channels of one output pixel.
// USE_T: src is the transposed T[r][u][ch]; else original (ch,H,W) layout.
template <bool USE_T>
__global__ __launch_bounds__(256) void fume_main(const float* __restrict__ src,
                                                 const float* __restrict__ Fm,
                                                 float* __restrict__ out) {
    int g = blockIdx.x * 256 + threadIdx.x;       // 0 .. 65536*SPLITS-1
    int part = g & (SPLITS - 1);
    int pix  = g >> 2;                            // SPLITS == 4
    int x = pix & (Ww - 1);
    int y = pix >> 8;
    int ch0 = part * CH_PER;

    // Epipolar line l1 = F^T x2, normalized (match reference op order).
    float xf = (float)x, yf = (float)y;
    float a = Fm[0] * xf + Fm[3] * yf + Fm[6];
    float b = Fm[1] * xf + Fm[4] * yf + Fm[7];
    float c = Fm[2] * xf + Fm[5] * yf + Fm[8];
    float n = sqrtf(a * a + b * b) + 1e-12f;
    a /= n; b /= n; c /= n;

    float acc[CH_PER];
#pragma unroll
    for (int k = 0; k < CH_PER; ++k) acc[k] = 0.f;

    if (fabsf(b) > 1e-6f) {                        // 'ok' mask
        float alpha = -a / b;                      // v(u) = alpha*u + beta
        float beta  = -c / b;

        // Analytic clip: contributions are exactly 0 unless v in (-1, 256).
        // Conservative outward rounding; per-u masks keep full correctness.
        int u_lo = 0, u_hi = Ww - 1;
        if (fabsf(alpha) > 1e-12f) {
            float t0 = (-1.f  - beta) / alpha;
            float t1 = (256.f - beta) / alpha;
            float tlo = fminf(t0, t1), thi = fmaxf(t0, t1);
            int lo = (int)floorf(tlo);             // cvt clamps on overflow
            int hi = (int)ceilf(thi);
            u_lo = lo > 0 ? lo : 0;
            u_hi = hi < (Ww - 1) ? hi : (Ww - 1);
        } else if (beta <= -1.f || beta >= 256.f) {
            u_hi = -1;                             // line never enters image
        }

        for (int u = u_lo; u <= u_hi; ++u) {
            float v  = fmaf(alpha, (float)u, beta);
            float rf = floorf(v);
            float f  = v - rf;
            int   ri = (int)rf;
            float w0 = (ri >= 0 && ri < Hh)       ? (1.f - f) : 0.f;  // m0
            float w1 = (ri >= -1 && ri <= Hh - 2) ? f         : 0.f;  // m1
            int r0 = ri < 0 ? 0 : (ri > Hh - 1 ? Hh - 1 : ri);
            int r1 = ri + 1 < 0 ? 0 : (ri + 1 > Hh - 1 ? Hh - 1 : ri + 1);
            if (USE_T) {
                const float4* p0 = reinterpret_cast<const float4*>(
                    src + (size_t)(r0 * Ww + u) * BCc + ch0);
                const float4* p1 = reinterpret_cast<const float4*>(
                    src + (size_t)(r1 * Ww + u) * BCc + ch0);
#pragma unroll
                for (int k = 0; k < CH_PER / 4; ++k) {
                    float4 s0 = p0[k];
                    float4 s1 = p1[k];
                    acc[4*k+0] = fmaf(w0, s0.x, fmaf(w1, s1.x, acc[4*k+0]));
                    acc[4*k+1] = fmaf(w0, s0.y, fmaf(w1, s1.y, acc[4*k+1]));
                    acc[4*k+2] = fmaf(w0, s0.z, fmaf(w1, s1.z, acc[4*k+2]));
                    acc[4*k+3] = fmaf(w0, s0.w, fmaf(w1, s1.w, acc[4*k+3]));
                }
            } else {
#pragma unroll
                for (int k = 0; k < CH_PER; ++k) {
                    float s0 = src[(size_t)(ch0 + k) * (Hh * Ww) + r0 * Ww + u];
                    float s1 = src[(size_t)(ch0 + k) * (Hh * Ww) + r1 * Ww + u];
                    acc[k] = fmaf(w0, s0, fmaf(w1, s1, acc[k]));
                }
            }
        }
    }

#pragma unroll
    for (int k = 0; k < CH_PER; ++k)
        out[(size_t)(ch0 + k) * (Hh * Ww) + pix] = acc[k];
}

extern "C" void kernel_launch(void* const* d_in, const int* in_sizes, int n_in,
                              void* d_out, int out_size, void* d_ws, size_t ws_size,
                              hipStream_t stream) {
    const float* view1 = (const float*)d_in[0];   // 8*4*256*256 fp32
    const float* Fm    = (const float*)d_in[1];   // 9 fp32, row-major 3x3
    float* out = (float*)d_out;

    constexpr size_t t_bytes = (size_t)Hh * Ww * BCc * sizeof(float);  // 8 MiB
    if (ws_size >= t_bytes) {
        float* T = (float*)d_ws;
        fume_transpose<<<(Hh * Ww) / 256, 256, 0, stream>>>(view1, T);
        fume_main<true><<<(Hh * Ww * SPLITS) / 256, 256, 0, stream>>>(T, Fm, out);
    } else {
        fume_main<false><<<(Hh * Ww * SPLITS) / 256, 256, 0, stream>>>(view1, Fm, out);
    }
}